// Round 7
// baseline (209.803 us; speedup 1.0000x reference)
//
#include <hip/hip_runtime.h>
#include <math.h>

#define D_PROJ 8192
#define C_IN   512
#define P_SP   196   // 14*14
#define NBATCH 32
#define NTP64  36    // symmetric tile-pairs of an 8x8 tiling (64-wide blocks)
#define LDA    132   // legacy path only

__device__ __constant__ int IT64[NTP64] = {
    0,0,0,0,0,0,0,0, 1,1,1,1,1,1,1, 2,2,2,2,2,2, 3,3,3,3,3, 4,4,4,4, 5,5,5, 6,6, 7};
__device__ __constant__ int JT64[NTP64] = {
    0,1,2,3,4,5,6,7, 1,2,3,4,5,6,7, 2,3,4,5,6,7, 3,4,5,6,7, 4,5,6,7, 5,6,7, 6,7, 7};

// ---------------------------------------------------------------------------
// global -> LDS direct DMA, 16B per lane (LDS dest wave-uniform + lane*16).
// ---------------------------------------------------------------------------
__device__ inline void gload_lds16(const float* gsrc, float* ldst)
{
    __builtin_amdgcn_global_load_lds(
        (const __attribute__((address_space(1))) void*)(gsrc),
        (__attribute__((address_space(3))) void*)(ldst),
        16, 0, 0);
}

// ---------------------------------------------------------------------------
// Count-sketch recovery: each row of S has one nonzero (+-1) at column h[row].
// ---------------------------------------------------------------------------
__global__ __launch_bounds__(256) void extract_sketch(
    const float* __restrict__ S1, const float* __restrict__ S2,
    int* __restrict__ h1, float* __restrict__ s1,
    int* __restrict__ h2, float* __restrict__ s2)
{
    const int row = blockIdx.x;            // 0..1023
    const int r   = row & (C_IN - 1);
    const float* S = (row < C_IN) ? S1 : S2;
    int*   h = (row < C_IN) ? h1 : h2;
    float* s = (row < C_IN) ? s1 : s2;
    const float4* rp = (const float4*)(S + (size_t)r * D_PROJ);
    for (int c = threadIdx.x; c < D_PROJ / 4; c += 256) {
        float4 v = rp[c];
        if (v.x != 0.0f) { h[r] = 4 * c;     s[r] = v.x; }
        if (v.y != 0.0f) { h[r] = 4 * c + 1; s[r] = v.y; }
        if (v.z != 0.0f) { h[r] = 4 * c + 2; s[r] = v.z; }
        if (v.w != 0.0f) { h[r] = 4 * c + 3; s[r] = v.w; }
    }
}

// ---------------------------------------------------------------------------
// x[b][c][p] -> xT[b][p][c]. 64x64 LDS-tiled transpose.
// ---------------------------------------------------------------------------
__global__ __launch_bounds__(256) void transpose_x(
    const float* __restrict__ x, float* __restrict__ xT)
{
    __shared__ float t[64][65];
    const int b  = blockIdx.z;
    const int pt = blockIdx.x;            // p tile 0..3
    const int ct = blockIdx.y;            // c tile 0..7
    const int tx = threadIdx.x & 63;
    const int ty = threadIdx.x >> 6;
    const int p0 = pt * 64, c0 = ct * 64;
    const float* xb  = x  + (size_t)b * C_IN * P_SP;
    float*       xtb = xT + (size_t)b * P_SP * C_IN;

    #pragma unroll
    for (int k = ty; k < 64; k += 4) {
        int p = p0 + tx;
        t[k][tx] = (p < P_SP) ? xb[(size_t)(c0 + k) * P_SP + p] : 0.0f;
    }
    __syncthreads();
    #pragma unroll
    for (int k = ty; k < 64; k += 4) {
        int p = p0 + k;
        if (p < P_SP) xtb[(size_t)p * C_IN + c0 + tx] = t[tx][k];
    }
}

// ---------------------------------------------------------------------------
// Symmetric Gram, 64x64 tiles, NO atomics: each block owns one (b, tile-pair)
// output tile over the FULL K=196 and writes it with plain float4 stores.
// Grid = 1152 = 8 XCD-slots x (4 batches x 36 tile-pairs) -> 4.5 blocks/CU.
// ---------------------------------------------------------------------------
__global__ __launch_bounds__(256, 6) void gram64(
    const float* __restrict__ xT, float* __restrict__ G)
{
    __shared__ __align__(16) float AB[2][28 * 64];   // 7 KB per buffer

    const int tid  = threadIdx.x;
    const int tx   = tid & 15;       // j quad (0..15)
    const int ty   = tid >> 4;       // i quad (0..15)
    const int wid  = tid >> 6;
    const int lane = tid & 63;

    const int id  = blockIdx.x;      // 0..1151
    const int xcd = id & 7;
    const int sub = id >> 3;         // 0..143
    const int b   = xcd + 8 * (sub / NTP64);
    const int t   = sub % NTP64;
    const int it  = IT64[t];
    const int jt  = JT64[t];
    const int cbA = it * 64, cbB = jt * 64;

    const float* xb = xT + (size_t)b * P_SP * C_IN;

    #define ISSUE(P0, BUF) do {                                               \
        for (int k = wid; k < 7; k += 4) {                                    \
            int fr   = 4 * k + (lane >> 4);                                   \
            int aSel = fr < 14;                                               \
            int pr   = aSel ? fr : fr - 14;                                   \
            int cb_  = aSel ? cbA : cbB;                                      \
            const float* g = xb + (size_t)((P0) + pr) * C_IN + cb_            \
                             + (lane & 15) * 4;                               \
            gload_lds16(g, &AB[BUF][k * 256]);                                \
        }                                                                     \
    } while (0)

    float acc[4][4];
    #pragma unroll
    for (int r = 0; r < 4; ++r)
        #pragma unroll
        for (int c = 0; c < 4; ++c) acc[r][c] = 0.0f;

    ISSUE(0, 0);
    __syncthreads();                               // chunk 0 ready

    for (int ch = 0; ch < 14; ++ch) {
        const int cur = ch & 1;
        if (ch + 1 < 14) ISSUE((ch + 1) * 14, cur ^ 1);
        #pragma unroll
        for (int pp = 0; pp < 14; ++pp) {
            float4 a = *(const float4*)(&AB[cur][pp * 64 + ty * 4]);
            float4 v = *(const float4*)(&AB[cur][(14 + pp) * 64 + tx * 4]);
            float av[4] = {a.x, a.y, a.z, a.w};
            float bv[4] = {v.x, v.y, v.z, v.w};
            #pragma unroll
            for (int r = 0; r < 4; ++r)
                #pragma unroll
                for (int c = 0; c < 4; ++c)
                    acc[r][c] = fmaf(av[r], bv[c], acc[r][c]);
        }
        __syncthreads();   // implicit vmcnt(0): next chunk's DMA landed
    }
    #undef ISSUE

    float* gt = G + (size_t)(b * NTP64 + t) * 4096;
    #pragma unroll
    for (int r = 0; r < 4; ++r) {
        float4 o = make_float4(acc[r][0], acc[r][1], acc[r][2], acc[r][3]);
        *(float4*)(&gt[(ty * 4 + r) * 64 + tx * 4]) = o;
    }
}

// ---------------------------------------------------------------------------
// Scatter G tiles through the count-sketch into per-block LDS histograms.
// Grid = 32 * ng (ng groups per batch; ng=36 -> one tile per block, same
// id-mapping as gram64 so G reads are same-XCD L2 hits; 4.5 blocks/CU at
// 40 KB LDS -> 4 resident -> latency finally overlapped).
// Params packed as one float4 {h1,s1,h2,s2} per channel -> single
// ds_read_b128 per emission pair. G loads register-prefetched before the
// atomic chain. Off-diagonal tiles also emit the mirrored (j,i) term.
//   mode 1: private slice at dest[(b*ng+grp)*8192]
//   mode 0: atomicAdd into dest[b*8192] (pre-zeroed d_out)
// ---------------------------------------------------------------------------
__global__ __launch_bounds__(256) void scatter64(
    const float* __restrict__ G,
    const int* __restrict__ h1, const float* __restrict__ s1,
    const int* __restrict__ h2, const float* __restrict__ s2,
    float* __restrict__ dest, int ng, int mode)
{
    __shared__ float hist[D_PROJ];                    // 32 KB
    __shared__ __align__(16) float4 pk[C_IN];         // 8 KB packed params

    const int tid = threadIdx.x;
    const int id  = blockIdx.x;      // 0..32*ng-1
    const int xcd = id & 7;
    const int sub = id >> 3;         // 0..4*ng-1
    const int b   = xcd + 8 * (sub / ng);
    const int grp = sub % ng;

    for (int k = tid; k < C_IN; k += 256) {
        float4 w;
        w.x = __int_as_float(h1[k]);  w.y = s1[k];
        w.z = __int_as_float(h2[k]);  w.w = s2[k];
        pk[k] = w;
    }
    for (int k = tid; k < D_PROJ; k += 256) hist[k] = 0.0f;
    __syncthreads();

    const int rr = tid >> 4;         // 0..15: row sub-index
    const int c0 = (tid & 15) * 4;   // col start

    for (int t = grp; t < NTP64; t += ng) {
        const int it = IT64[t], jt = JT64[t];
        const int diag = (it == jt);
        const float* gt = G + (size_t)(b * NTP64 + t) * 4096;

        // All 4 tile-rows' float4 loads issued together (stay in flight).
        float4 g[4];
        #pragma unroll
        for (int n = 0; n < 4; ++n)
            g[n] = *(const float4*)(gt + n * 1024 + tid * 4);

        #pragma unroll
        for (int n = 0; n < 4; ++n) {
            const int r  = n * 16 + rr;
            const int gi = it * 64 + r;
            float4 wr = pk[gi];                  // broadcast across 16 lanes
            int   hA = __float_as_int(wr.x);
            float sA = wr.y;
            int   hM = __float_as_int(wr.z);     // mirror: row as h2 role
            float sM = wr.w;
            float gv[4] = {g[n].x, g[n].y, g[n].z, g[n].w};
            #pragma unroll
            for (int k = 0; k < 4; ++k) {
                int gj = jt * 64 + c0 + k;
                float4 wc = pk[gj];              // one b128 read: h1,s1,h2,s2
                int d1 = (hA + __float_as_int(wc.z)) & (D_PROJ - 1);
                atomicAdd(&hist[d1], sA * wc.w * gv[k]);
                if (!diag) {
                    int d2 = (__float_as_int(wc.x) + hM) & (D_PROJ - 1);
                    atomicAdd(&hist[d2], wc.y * sM * gv[k]);
                }
            }
        }
    }
    __syncthreads();

    if (mode == 1) {
        float* pb = dest + (size_t)(b * ng + grp) * D_PROJ;
        for (int k = tid * 4; k < D_PROJ; k += 1024)
            *(float4*)(pb + k) = *(const float4*)(hist + k);
    } else {
        float* pb = dest + (size_t)b * D_PROJ;
        for (int k = tid; k < D_PROJ; k += 256) atomicAdd(&pb[k], hist[k]);
    }
}

// ---------------------------------------------------------------------------
__device__ inline float ssqrt_scale(float v, float inv)
{
    float r = sqrtf(fabsf(v) + 1e-8f) * inv;
    return (v > 0.0f) ? r : ((v < 0.0f) ? -r : 0.0f);
}

__global__ __launch_bounds__(256) void finalize_partial(
    const float* __restrict__ partial, float* __restrict__ out, int ns)
{
    const int b   = blockIdx.x;
    const int tid = threadIdx.x;
    const float* base = partial + (size_t)b * ns * D_PROJ;

    float4 acc[8];
    #pragma unroll
    for (int n = 0; n < 8; ++n) acc[n] = make_float4(0.f, 0.f, 0.f, 0.f);

    for (int t = 0; t < ns; ++t) {
        const float* bt = base + (size_t)t * D_PROJ;
        #pragma unroll
        for (int n = 0; n < 8; ++n) {
            float4 v = *(const float4*)(bt + tid * 4 + n * 1024);
            acc[n].x += v.x; acc[n].y += v.y; acc[n].z += v.z; acc[n].w += v.w;
        }
    }

    float s = 0.0f;
    #pragma unroll
    for (int n = 0; n < 8; ++n)
        s += fabsf(acc[n].x) + fabsf(acc[n].y) + fabsf(acc[n].z) + fabsf(acc[n].w);
    #pragma unroll
    for (int off = 32; off > 0; off >>= 1) s += __shfl_down(s, off, 64);
    __shared__ float red[4];
    if ((tid & 63) == 0) red[tid >> 6] = s;
    __syncthreads();
    float total = red[0] + red[1] + red[2] + red[3];
    float inv   = 1.0f / fmaxf(sqrtf(total + (float)D_PROJ * 1e-8f), 1e-12f);

    float* ob = out + (size_t)b * D_PROJ;
    #pragma unroll
    for (int n = 0; n < 8; ++n) {
        const int k = tid * 4 + n * 1024;
        float4 a = acc[n];
        float4 r;
        r.x = ssqrt_scale(a.x, inv);
        r.y = ssqrt_scale(a.y, inv);
        r.z = ssqrt_scale(a.z, inv);
        r.w = ssqrt_scale(a.w, inv);
        *(float4*)(ob + k) = r;
    }
}

__global__ __launch_bounds__(256) void finalize_inplace(float* __restrict__ out)
{
    const int b = blockIdx.x;
    float* p = out + (size_t)b * D_PROJ;
    const int tid = threadIdx.x;

    float s = 0.0f;
    for (int d = tid; d < D_PROJ; d += 256) s += fabsf(p[d]);
    #pragma unroll
    for (int off = 32; off > 0; off >>= 1) s += __shfl_down(s, off, 64);
    __shared__ float red[4];
    if ((tid & 63) == 0) red[tid >> 6] = s;
    __syncthreads();
    float total = red[0] + red[1] + red[2] + red[3];
    float inv   = 1.0f / fmaxf(sqrtf(total + (float)D_PROJ * 1e-8f), 1e-12f);

    for (int d = tid; d < D_PROJ; d += 256) {
        float v = p[d];
        float r = sqrtf(fabsf(v) + 1e-8f) * inv;
        p[d] = (v > 0.0f) ? r : ((v < 0.0f) ? -r : 0.0f);
    }
}

// ---------------------------------------------------------------------------
// Legacy fused fallback (tiny ws): R1-style gram+scatter with d_out atomics.
// ---------------------------------------------------------------------------
__global__ __launch_bounds__(256) void gram_scatter_legacy(
    const float* __restrict__ x,
    const int* __restrict__ h1, const float* __restrict__ s1,
    const int* __restrict__ h2, const float* __restrict__ s2,
    float* __restrict__ pool)
{
    __shared__ float accL[D_PROJ];
    __shared__ __align__(16) float As[14 * LDA];
    __shared__ __align__(16) float Bs[14 * LDA];
    __shared__ int   h1L[128];
    __shared__ float s1L[128];
    __shared__ int   h2L[128];
    __shared__ float s2L[128];

    const int tid = threadIdx.x;
    const int tx  = tid & 15;
    const int ty  = tid >> 4;
    const int id  = blockIdx.x;
    const int xcd = id & 7;
    const int rem = id >> 3;
    const int tile = rem & 15;
    const int b   = xcd + 8 * (rem >> 4);
    const int it  = tile >> 2;
    const int jt  = tile & 3;

    if (tid < 128) {
        h1L[tid] = h1[it * 128 + tid];
        s1L[tid] = s1[it * 128 + tid];
        h2L[tid] = h2[jt * 128 + tid];
        s2L[tid] = s2[jt * 128 + tid];
    }
    for (int k = tid; k < D_PROJ; k += 256) accL[k] = 0.0f;

    const float* xi = x + ((size_t)b * C_IN + it * 128) * P_SP;
    const float* xj = x + ((size_t)b * C_IN + jt * 128) * P_SP;

    float acc[8][8];
    #pragma unroll
    for (int r = 0; r < 8; ++r)
        #pragma unroll
        for (int c = 0; c < 8; ++c) acc[r][c] = 0.0f;

    for (int ch = 0; ch < 14; ++ch) {
        const int p0 = ch * 14;
        __syncthreads();
        #pragma unroll
        for (int e = 0; e < 7; ++e) {
            int idx = e * 256 + tid;
            int il  = idx / 14;
            int pp  = idx - il * 14;
            As[pp * LDA + il] = xi[il * P_SP + p0 + pp];
            Bs[pp * LDA + il] = xj[il * P_SP + p0 + pp];
        }
        __syncthreads();
        #pragma unroll
        for (int pp = 0; pp < 14; ++pp) {
            const float* ap = &As[pp * LDA];
            const float* bp = &Bs[pp * LDA];
            float4 a0 = *(const float4*)(ap + ty * 4);
            float4 a1 = *(const float4*)(ap + 64 + ty * 4);
            float4 b0 = *(const float4*)(bp + tx * 4);
            float4 b1 = *(const float4*)(bp + 64 + tx * 4);
            float av[8] = {a0.x, a0.y, a0.z, a0.w, a1.x, a1.y, a1.z, a1.w};
            float bv[8] = {b0.x, b0.y, b0.z, b0.w, b1.x, b1.y, b1.z, b1.w};
            #pragma unroll
            for (int r = 0; r < 8; ++r)
                #pragma unroll
                for (int c = 0; c < 8; ++c)
                    acc[r][c] = fmaf(av[r], bv[c], acc[r][c]);
        }
    }

    #pragma unroll
    for (int r = 0; r < 8; ++r) {
        int   il = (r < 4) ? (ty * 4 + r) : (64 + ty * 4 + (r - 4));
        int   hA = h1L[il];
        float sA = s1L[il];
        #pragma unroll
        for (int c = 0; c < 8; ++c) {
            int jl = (c < 4) ? (tx * 4 + c) : (64 + tx * 4 + (c - 4));
            int d  = (hA + h2L[jl]) & (D_PROJ - 1);
            atomicAdd(&accL[d], sA * s2L[jl] * acc[r][c]);
        }
    }
    __syncthreads();

    float* pb = pool + (size_t)b * D_PROJ;
    for (int k = tid; k < D_PROJ; k += 256) atomicAdd(&pb[k], accL[k]);
}

// ---------------------------------------------------------------------------
extern "C" void kernel_launch(void* const* d_in, const int* in_sizes, int n_in,
                              void* d_out, int out_size, void* d_ws, size_t ws_size,
                              hipStream_t stream)
{
    const float* x  = (const float*)d_in[0];   // [32, 512, 14, 14]
    const float* S1 = (const float*)d_in[1];   // [512, 8192]
    const float* S2 = (const float*)d_in[2];   // [512, 8192]
    float* out = (float*)d_out;                // [32, 8192]

    char* ws = (char*)d_ws;
    int*   h1 = (int*)(ws);
    float* s1 = (float*)(ws + 2048);
    int*   h2 = (int*)(ws + 4096);
    float* s2 = (float*)(ws + 6144);

    const size_t XT_BYTES = (size_t)NBATCH * P_SP * C_IN * sizeof(float);       // 12.85 MB
    const size_t G_BYTES  = (size_t)NBATCH * NTP64 * 4096 * sizeof(float);      // 18.87 MB
    const size_t SLICE    = (size_t)NBATCH * D_PROJ * sizeof(float);            //  1.05 MB per group

    float* xT      = (float*)(ws + 8192);
    float* G       = (float*)(ws + 8192 + XT_BYTES);
    float* partial = (float*)(ws + 8192 + XT_BYTES + G_BYTES);

    const size_t base = 8192 + XT_BYTES + G_BYTES;

    extract_sketch<<<1024, 256, 0, stream>>>(S1, S2, h1, s1, h2, s2);

    if (ws_size >= base) {
        // Pick the largest slice tier that fits: 36 (1 tile/block) > 12 > 8.
        int ng = 0;
        if      (ws_size >= base + 36 * SLICE) ng = 36;
        else if (ws_size >= base + 12 * SLICE) ng = 12;
        else if (ws_size >= base +  8 * SLICE) ng = 8;

        transpose_x<<<dim3(4, 8, NBATCH), 256, 0, stream>>>(x, xT);
        gram64<<<NBATCH * NTP64, 256, 0, stream>>>(xT, G);
        if (ng > 0) {
            scatter64<<<NBATCH * ng, 256, 0, stream>>>(G, h1, s1, h2, s2, partial, ng, 1);
            finalize_partial<<<NBATCH, 256, 0, stream>>>(partial, out, ng);
        } else {
            hipMemsetAsync(d_out, 0, (size_t)out_size * sizeof(float), stream);
            scatter64<<<NBATCH * 8, 256, 0, stream>>>(G, h1, s1, h2, s2, out, 8, 0);
            finalize_inplace<<<NBATCH, 256, 0, stream>>>(out);
        }
    } else {
        hipMemsetAsync(d_out, 0, (size_t)out_size * sizeof(float), stream);
        gram_scatter_legacy<<<512, 256, 0, stream>>>(x, h1, s1, h2, s2, out);
        finalize_inplace<<<NBATCH, 256, 0, stream>>>(out);
    }
}

// Round 8
// 203.530 us; speedup vs baseline: 1.0308x; 1.0308x over previous
//
#include <hip/hip_runtime.h>
#include <math.h>

#define D_PROJ 8192
#define C_IN   512
#define P_SP   196   // 14*14
#define NBATCH 32
#define NTP64  36    // symmetric tile-pairs of an 8x8 tiling (64-wide blocks)
#define LDA    132   // legacy path only

__device__ __constant__ int IT64[NTP64] = {
    0,0,0,0,0,0,0,0, 1,1,1,1,1,1,1, 2,2,2,2,2,2, 3,3,3,3,3, 4,4,4,4, 5,5,5, 6,6, 7};
__device__ __constant__ int JT64[NTP64] = {
    0,1,2,3,4,5,6,7, 1,2,3,4,5,6,7, 2,3,4,5,6,7, 3,4,5,6,7, 4,5,6,7, 5,6,7, 6,7, 7};

// ---------------------------------------------------------------------------
// Native fp32 atomic add (ds_add_f32 / global_atomic_add_f32). Plain
// atomicAdd on fp32 compiles to a CAS LOOP without -munsafe-fp-atomics —
// 5-10x slower; this was the session-long hidden cost on every atomic path.
// ---------------------------------------------------------------------------
__device__ inline void fadd_native(float* p, float v) { unsafeAtomicAdd(p, v); }

// ---------------------------------------------------------------------------
// global -> LDS direct DMA, 16B per lane (LDS dest wave-uniform + lane*16).
// ---------------------------------------------------------------------------
__device__ inline void gload_lds16(const float* gsrc, float* ldst)
{
    __builtin_amdgcn_global_load_lds(
        (const __attribute__((address_space(1))) void*)(gsrc),
        (__attribute__((address_space(3))) void*)(ldst),
        16, 0, 0);
}

// ---------------------------------------------------------------------------
// prep: one dispatch doing both input-prep jobs (saves a launch gap).
//   blocks 0..1023   : count-sketch recovery (rows of S1 then S2)
//   blocks 1024..2047: x[b][c][p] -> xT[b][p][c] 64x64 tiled transpose
// ---------------------------------------------------------------------------
__global__ __launch_bounds__(256) void prep(
    const float* __restrict__ S1, const float* __restrict__ S2,
    const float* __restrict__ x,
    int* __restrict__ h1, float* __restrict__ s1,
    int* __restrict__ h2, float* __restrict__ s2,
    float* __restrict__ xT)
{
    __shared__ float t[64][65];
    const int bid = blockIdx.x;

    if (bid < 1024) {
        const int r = bid & (C_IN - 1);
        const float* S = (bid < C_IN) ? S1 : S2;
        int*   h = (bid < C_IN) ? h1 : h2;
        float* s = (bid < C_IN) ? s1 : s2;
        const float4* rp = (const float4*)(S + (size_t)r * D_PROJ);
        for (int c = threadIdx.x; c < D_PROJ / 4; c += 256) {
            float4 v = rp[c];
            if (v.x != 0.0f) { h[r] = 4 * c;     s[r] = v.x; }
            if (v.y != 0.0f) { h[r] = 4 * c + 1; s[r] = v.y; }
            if (v.z != 0.0f) { h[r] = 4 * c + 2; s[r] = v.z; }
            if (v.w != 0.0f) { h[r] = 4 * c + 3; s[r] = v.w; }
        }
        return;
    }

    const int idx = bid - 1024;
    const int pt  = idx & 3;
    const int ct  = (idx >> 2) & 7;
    const int b   = idx >> 5;
    const int tx  = threadIdx.x & 63;
    const int ty  = threadIdx.x >> 6;
    const int p0  = pt * 64, c0 = ct * 64;
    const float* xb  = x  + (size_t)b * C_IN * P_SP;
    float*       xtb = xT + (size_t)b * P_SP * C_IN;

    #pragma unroll
    for (int k = ty; k < 64; k += 4) {
        int p = p0 + tx;
        t[k][tx] = (p < P_SP) ? xb[(size_t)(c0 + k) * P_SP + p] : 0.0f;
    }
    __syncthreads();
    #pragma unroll
    for (int k = ty; k < 64; k += 4) {
        int p = p0 + k;
        if (p < P_SP) xtb[(size_t)p * C_IN + c0 + tx] = t[tx][k];
    }
}

// ---------------------------------------------------------------------------
// Symmetric Gram, 64x64 tiles, NO atomics: each block owns one (b, tile-pair)
// output tile over the FULL K=196, plain float4 stores.
// Grid = 1152 = 8 XCD-slots x (4 batches x 36 tile-pairs).
// ---------------------------------------------------------------------------
__global__ __launch_bounds__(256, 6) void gram64(
    const float* __restrict__ xT, float* __restrict__ G)
{
    __shared__ __align__(16) float AB[2][28 * 64];   // 7 KB per buffer

    const int tid  = threadIdx.x;
    const int tx   = tid & 15;       // j quad (0..15)
    const int ty   = tid >> 4;       // i quad (0..15)
    const int wid  = tid >> 6;
    const int lane = tid & 63;

    const int id  = blockIdx.x;      // 0..1151
    const int xcd = id & 7;
    const int sub = id >> 3;         // 0..143
    const int b   = xcd + 8 * (sub / NTP64);
    const int t   = sub % NTP64;
    const int it  = IT64[t];
    const int jt  = JT64[t];
    const int cbA = it * 64, cbB = jt * 64;

    const float* xb = xT + (size_t)b * P_SP * C_IN;

    #define ISSUE(P0, BUF) do {                                               \
        for (int k = wid; k < 7; k += 4) {                                    \
            int fr   = 4 * k + (lane >> 4);                                   \
            int aSel = fr < 14;                                               \
            int pr   = aSel ? fr : fr - 14;                                   \
            int cb_  = aSel ? cbA : cbB;                                      \
            const float* g = xb + (size_t)((P0) + pr) * C_IN + cb_            \
                             + (lane & 15) * 4;                               \
            gload_lds16(g, &AB[BUF][k * 256]);                                \
        }                                                                     \
    } while (0)

    float acc[4][4];
    #pragma unroll
    for (int r = 0; r < 4; ++r)
        #pragma unroll
        for (int c = 0; c < 4; ++c) acc[r][c] = 0.0f;

    ISSUE(0, 0);
    __syncthreads();                               // chunk 0 ready

    for (int ch = 0; ch < 14; ++ch) {
        const int cur = ch & 1;
        if (ch + 1 < 14) ISSUE((ch + 1) * 14, cur ^ 1);
        #pragma unroll
        for (int pp = 0; pp < 14; ++pp) {
            float4 a = *(const float4*)(&AB[cur][pp * 64 + ty * 4]);
            float4 v = *(const float4*)(&AB[cur][(14 + pp) * 64 + tx * 4]);
            float av[4] = {a.x, a.y, a.z, a.w};
            float bv[4] = {v.x, v.y, v.z, v.w};
            #pragma unroll
            for (int r = 0; r < 4; ++r)
                #pragma unroll
                for (int c = 0; c < 4; ++c)
                    acc[r][c] = fmaf(av[r], bv[c], acc[r][c]);
        }
        __syncthreads();   // implicit vmcnt(0): next chunk's DMA landed
    }
    #undef ISSUE

    float* gt = G + (size_t)(b * NTP64 + t) * 4096;
    #pragma unroll
    for (int r = 0; r < 4; ++r) {
        float4 o = make_float4(acc[r][0], acc[r][1], acc[r][2], acc[r][3]);
        *(float4*)(&gt[(ty * 4 + r) * 64 + tx * 4]) = o;
    }
}

// ---------------------------------------------------------------------------
// Scatter G tiles through the count-sketch into per-block LDS histograms.
// Grid = 32*ng; ng=36 -> one tile per block, same id-map as gram64 (same-XCD
// L2 hits on G). Atomics are NATIVE ds_add_f32 via unsafeAtomicAdd.
//   mode 1: private slice at dest[(b*ng+grp)*8192]
//   mode 0: native global atomic add into dest[b*8192] (pre-zeroed d_out)
// ---------------------------------------------------------------------------
__global__ __launch_bounds__(256) void scatter64(
    const float* __restrict__ G,
    const int* __restrict__ h1, const float* __restrict__ s1,
    const int* __restrict__ h2, const float* __restrict__ s2,
    float* __restrict__ dest, int ng, int mode)
{
    __shared__ __align__(16) float hist[D_PROJ];      // 32 KB
    __shared__ __align__(16) float4 pk[C_IN];         // 8 KB packed params

    const int tid = threadIdx.x;
    const int id  = blockIdx.x;      // 0..32*ng-1
    const int xcd = id & 7;
    const int sub = id >> 3;         // 0..4*ng-1
    const int b   = xcd + 8 * (sub / ng);
    const int grp = sub % ng;

    for (int k = tid; k < C_IN; k += 256) {
        float4 w;
        w.x = __int_as_float(h1[k]);  w.y = s1[k];
        w.z = __int_as_float(h2[k]);  w.w = s2[k];
        pk[k] = w;
    }
    for (int k = tid * 4; k < D_PROJ; k += 1024)
        *(float4*)(hist + k) = make_float4(0.f, 0.f, 0.f, 0.f);
    __syncthreads();

    const int rr = tid >> 4;         // 0..15: row sub-index
    const int c0 = (tid & 15) * 4;   // col start

    for (int t = grp; t < NTP64; t += ng) {
        const int it = IT64[t], jt = JT64[t];
        const int diag = (it == jt);
        const float* gt = G + (size_t)(b * NTP64 + t) * 4096;

        float4 g[4];
        #pragma unroll
        for (int n = 0; n < 4; ++n)
            g[n] = *(const float4*)(gt + n * 1024 + tid * 4);

        #pragma unroll
        for (int n = 0; n < 4; ++n) {
            const int r  = n * 16 + rr;
            const int gi = it * 64 + r;
            float4 wr = pk[gi];                  // broadcast across 16 lanes
            int   hA = __float_as_int(wr.x);
            float sA = wr.y;
            int   hM = __float_as_int(wr.z);     // mirror: row as h2 role
            float sM = wr.w;
            float gv[4] = {g[n].x, g[n].y, g[n].z, g[n].w};
            #pragma unroll
            for (int k = 0; k < 4; ++k) {
                int gj = jt * 64 + c0 + k;
                float4 wc = pk[gj];              // one b128 read: h1,s1,h2,s2
                int d1 = (hA + __float_as_int(wc.z)) & (D_PROJ - 1);
                fadd_native(&hist[d1], sA * wc.w * gv[k]);
                if (!diag) {
                    int d2 = (__float_as_int(wc.x) + hM) & (D_PROJ - 1);
                    fadd_native(&hist[d2], wc.y * sM * gv[k]);
                }
            }
        }
    }
    __syncthreads();

    if (mode == 1) {
        float* pb = dest + (size_t)(b * ng + grp) * D_PROJ;
        for (int k = tid * 4; k < D_PROJ; k += 1024)
            *(float4*)(pb + k) = *(const float4*)(hist + k);
    } else {
        float* pb = dest + (size_t)b * D_PROJ;
        for (int k = tid; k < D_PROJ; k += 256) fadd_native(&pb[k], hist[k]);
    }
}

// ---------------------------------------------------------------------------
__device__ inline float ssqrt_scale(float v, float inv)
{
    float r = sqrtf(fabsf(v) + 1e-8f) * inv;
    return (v > 0.0f) ? r : ((v < 0.0f) ? -r : 0.0f);
}

__global__ __launch_bounds__(256) void finalize_partial(
    const float* __restrict__ partial, float* __restrict__ out, int ns)
{
    const int b   = blockIdx.x;
    const int tid = threadIdx.x;
    const float* base = partial + (size_t)b * ns * D_PROJ;

    float4 acc[8];
    #pragma unroll
    for (int n = 0; n < 8; ++n) acc[n] = make_float4(0.f, 0.f, 0.f, 0.f);

    for (int t = 0; t < ns; ++t) {
        const float* bt = base + (size_t)t * D_PROJ;
        #pragma unroll
        for (int n = 0; n < 8; ++n) {
            float4 v = *(const float4*)(bt + tid * 4 + n * 1024);
            acc[n].x += v.x; acc[n].y += v.y; acc[n].z += v.z; acc[n].w += v.w;
        }
    }

    float s = 0.0f;
    #pragma unroll
    for (int n = 0; n < 8; ++n)
        s += fabsf(acc[n].x) + fabsf(acc[n].y) + fabsf(acc[n].z) + fabsf(acc[n].w);
    #pragma unroll
    for (int off = 32; off > 0; off >>= 1) s += __shfl_down(s, off, 64);
    __shared__ float red[4];
    if ((tid & 63) == 0) red[tid >> 6] = s;
    __syncthreads();
    float total = red[0] + red[1] + red[2] + red[3];
    float inv   = 1.0f / fmaxf(sqrtf(total + (float)D_PROJ * 1e-8f), 1e-12f);

    float* ob = out + (size_t)b * D_PROJ;
    #pragma unroll
    for (int n = 0; n < 8; ++n) {
        const int k = tid * 4 + n * 1024;
        float4 a = acc[n];
        float4 r;
        r.x = ssqrt_scale(a.x, inv);
        r.y = ssqrt_scale(a.y, inv);
        r.z = ssqrt_scale(a.z, inv);
        r.w = ssqrt_scale(a.w, inv);
        *(float4*)(ob + k) = r;
    }
}

__global__ __launch_bounds__(256) void finalize_inplace(float* __restrict__ out)
{
    const int b = blockIdx.x;
    float* p = out + (size_t)b * D_PROJ;
    const int tid = threadIdx.x;

    float s = 0.0f;
    for (int d = tid; d < D_PROJ; d += 256) s += fabsf(p[d]);
    #pragma unroll
    for (int off = 32; off > 0; off >>= 1) s += __shfl_down(s, off, 64);
    __shared__ float red[4];
    if ((tid & 63) == 0) red[tid >> 6] = s;
    __syncthreads();
    float total = red[0] + red[1] + red[2] + red[3];
    float inv   = 1.0f / fmaxf(sqrtf(total + (float)D_PROJ * 1e-8f), 1e-12f);

    for (int d = tid; d < D_PROJ; d += 256) {
        float v = p[d];
        float r = sqrtf(fabsf(v) + 1e-8f) * inv;
        p[d] = (v > 0.0f) ? r : ((v < 0.0f) ? -r : 0.0f);
    }
}

// ---------------------------------------------------------------------------
// Legacy fused fallback (tiny ws): R1-style gram+scatter with d_out atomics.
// ---------------------------------------------------------------------------
__global__ __launch_bounds__(256) void gram_scatter_legacy(
    const float* __restrict__ x,
    const int* __restrict__ h1, const float* __restrict__ s1,
    const int* __restrict__ h2, const float* __restrict__ s2,
    float* __restrict__ pool)
{
    __shared__ float accL[D_PROJ];
    __shared__ __align__(16) float As[14 * LDA];
    __shared__ __align__(16) float Bs[14 * LDA];
    __shared__ int   h1L[128];
    __shared__ float s1L[128];
    __shared__ int   h2L[128];
    __shared__ float s2L[128];

    const int tid = threadIdx.x;
    const int tx  = tid & 15;
    const int ty  = tid >> 4;
    const int id  = blockIdx.x;
    const int xcd = id & 7;
    const int rem = id >> 3;
    const int tile = rem & 15;
    const int b   = xcd + 8 * (rem >> 4);
    const int it  = tile >> 2;
    const int jt  = tile & 3;

    if (tid < 128) {
        h1L[tid] = h1[it * 128 + tid];
        s1L[tid] = s1[it * 128 + tid];
        h2L[tid] = h2[jt * 128 + tid];
        s2L[tid] = s2[jt * 128 + tid];
    }
    for (int k = tid; k < D_PROJ; k += 256) accL[k] = 0.0f;

    const float* xi = x + ((size_t)b * C_IN + it * 128) * P_SP;
    const float* xj = x + ((size_t)b * C_IN + jt * 128) * P_SP;

    float acc[8][8];
    #pragma unroll
    for (int r = 0; r < 8; ++r)
        #pragma unroll
        for (int c = 0; c < 8; ++c) acc[r][c] = 0.0f;

    for (int ch = 0; ch < 14; ++ch) {
        const int p0 = ch * 14;
        __syncthreads();
        #pragma unroll
        for (int e = 0; e < 7; ++e) {
            int idx = e * 256 + tid;
            int il  = idx / 14;
            int pp  = idx - il * 14;
            As[pp * LDA + il] = xi[il * P_SP + p0 + pp];
            Bs[pp * LDA + il] = xj[il * P_SP + p0 + pp];
        }
        __syncthreads();
        #pragma unroll
        for (int pp = 0; pp < 14; ++pp) {
            const float* ap = &As[pp * LDA];
            const float* bp = &Bs[pp * LDA];
            float4 a0 = *(const float4*)(ap + ty * 4);
            float4 a1 = *(const float4*)(ap + 64 + ty * 4);
            float4 b0 = *(const float4*)(bp + tx * 4);
            float4 b1 = *(const float4*)(bp + 64 + tx * 4);
            float av[8] = {a0.x, a0.y, a0.z, a0.w, a1.x, a1.y, a1.z, a1.w};
            float bv[8] = {b0.x, b0.y, b0.z, b0.w, b1.x, b1.y, b1.z, b1.w};
            #pragma unroll
            for (int r = 0; r < 8; ++r)
                #pragma unroll
                for (int c = 0; c < 8; ++c)
                    acc[r][c] = fmaf(av[r], bv[c], acc[r][c]);
        }
    }

    #pragma unroll
    for (int r = 0; r < 8; ++r) {
        int   il = (r < 4) ? (ty * 4 + r) : (64 + ty * 4 + (r - 4));
        int   hA = h1L[il];
        float sA = s1L[il];
        #pragma unroll
        for (int c = 0; c < 8; ++c) {
            int jl = (c < 4) ? (tx * 4 + c) : (64 + tx * 4 + (c - 4));
            int d  = (hA + h2L[jl]) & (D_PROJ - 1);
            fadd_native(&accL[d], sA * s2L[jl] * acc[r][c]);
        }
    }
    __syncthreads();

    float* pb = pool + (size_t)b * D_PROJ;
    for (int k = tid; k < D_PROJ; k += 256) fadd_native(&pb[k], accL[k]);
}

// ---------------------------------------------------------------------------
extern "C" void kernel_launch(void* const* d_in, const int* in_sizes, int n_in,
                              void* d_out, int out_size, void* d_ws, size_t ws_size,
                              hipStream_t stream)
{
    const float* x  = (const float*)d_in[0];   // [32, 512, 14, 14]
    const float* S1 = (const float*)d_in[1];   // [512, 8192]
    const float* S2 = (const float*)d_in[2];   // [512, 8192]
    float* out = (float*)d_out;                // [32, 8192]

    char* ws = (char*)d_ws;
    int*   h1 = (int*)(ws);
    float* s1 = (float*)(ws + 2048);
    int*   h2 = (int*)(ws + 4096);
    float* s2 = (float*)(ws + 6144);

    const size_t XT_BYTES = (size_t)NBATCH * P_SP * C_IN * sizeof(float);       // 12.85 MB
    const size_t G_BYTES  = (size_t)NBATCH * NTP64 * 4096 * sizeof(float);      // 18.87 MB
    const size_t SLICE    = (size_t)NBATCH * D_PROJ * sizeof(float);            //  1.05 MB per group

    float* xT      = (float*)(ws + 8192);
    float* G       = (float*)(ws + 8192 + XT_BYTES);
    float* partial = (float*)(ws + 8192 + XT_BYTES + G_BYTES);

    const size_t base = 8192 + XT_BYTES + G_BYTES;

    if (ws_size >= base) {
        // Pick the largest slice tier that fits: 36 (1 tile/block) > 12 > 8.
        int ng = 0;
        if      (ws_size >= base + 36 * SLICE) ng = 36;
        else if (ws_size >= base + 12 * SLICE) ng = 12;
        else if (ws_size >= base +  8 * SLICE) ng = 8;

        prep<<<2048, 256, 0, stream>>>(S1, S2, x, h1, s1, h2, s2, xT);
        gram64<<<NBATCH * NTP64, 256, 0, stream>>>(xT, G);
        if (ng > 0) {
            scatter64<<<NBATCH * ng, 256, 0, stream>>>(G, h1, s1, h2, s2, partial, ng, 1);
            finalize_partial<<<NBATCH, 256, 0, stream>>>(partial, out, ng);
        } else {
            hipMemsetAsync(d_out, 0, (size_t)out_size * sizeof(float), stream);
            scatter64<<<NBATCH * 8, 256, 0, stream>>>(G, h1, s1, h2, s2, out, 8, 0);
            finalize_inplace<<<NBATCH, 256, 0, stream>>>(out);
        }
    } else {
        hipMemsetAsync(d_out, 0, (size_t)out_size * sizeof(float), stream);
        prep<<<2048, 256, 0, stream>>>(S1, S2, x, h1, s1, h2, s2, xT); // xT unused below but harmless if ws tiny? no: guard
        gram_scatter_legacy<<<512, 256, 0, stream>>>(x, h1, s1, h2, s2, out);
        finalize_inplace<<<NBATCH, 256, 0, stream>>>(out);
    }
}

// Round 9
// 201.794 us; speedup vs baseline: 1.0397x; 1.0086x over previous
//
#include <hip/hip_runtime.h>
#include <math.h>

#define D_PROJ 8192
#define C_IN   512
#define P_SP   196   // 14*14
#define NBATCH 32
#define NTP64  36    // symmetric tile-pairs of an 8x8 tiling (64-wide blocks)
#define LDA    132   // legacy path only

__device__ __constant__ int IT64[NTP64] = {
    0,0,0,0,0,0,0,0, 1,1,1,1,1,1,1, 2,2,2,2,2,2, 3,3,3,3,3, 4,4,4,4, 5,5,5, 6,6, 7};
__device__ __constant__ int JT64[NTP64] = {
    0,1,2,3,4,5,6,7, 1,2,3,4,5,6,7, 2,3,4,5,6,7, 3,4,5,6,7, 4,5,6,7, 5,6,7, 6,7, 7};

// Native fp32 atomic add (ds_add_f32 / global_atomic_add_f32).
__device__ inline void fadd_native(float* p, float v) { unsafeAtomicAdd(p, v); }

// global -> LDS direct DMA, 16B per lane (LDS dest wave-uniform + lane*16).
__device__ inline void gload_lds16(const float* gsrc, float* ldst)
{
    __builtin_amdgcn_global_load_lds(
        (const __attribute__((address_space(1))) void*)(gsrc),
        (__attribute__((address_space(3))) void*)(ldst),
        16, 0, 0);
}

// ---------------------------------------------------------------------------
// prep: blocks 0..1023 recover the count-sketches; blocks 1024.. transpose x
// (only when do_xpose != 0; the legacy tier has no xT buffer).
// ---------------------------------------------------------------------------
__global__ __launch_bounds__(256) void prep(
    const float* __restrict__ S1, const float* __restrict__ S2,
    const float* __restrict__ x,
    int* __restrict__ h1, float* __restrict__ s1,
    int* __restrict__ h2, float* __restrict__ s2,
    float* __restrict__ xT, int do_xpose)
{
    __shared__ float t[64][65];
    const int bid = blockIdx.x;

    if (bid < 1024) {
        const int r = bid & (C_IN - 1);
        const float* S = (bid < C_IN) ? S1 : S2;
        int*   h = (bid < C_IN) ? h1 : h2;
        float* s = (bid < C_IN) ? s1 : s2;
        const float4* rp = (const float4*)(S + (size_t)r * D_PROJ);
        for (int c = threadIdx.x; c < D_PROJ / 4; c += 256) {
            float4 v = rp[c];
            if (v.x != 0.0f) { h[r] = 4 * c;     s[r] = v.x; }
            if (v.y != 0.0f) { h[r] = 4 * c + 1; s[r] = v.y; }
            if (v.z != 0.0f) { h[r] = 4 * c + 2; s[r] = v.z; }
            if (v.w != 0.0f) { h[r] = 4 * c + 3; s[r] = v.w; }
        }
        return;
    }
    if (!do_xpose) return;

    const int idx = bid - 1024;
    const int pt  = idx & 3;
    const int ct  = (idx >> 2) & 7;
    const int b   = idx >> 5;
    const int tx  = threadIdx.x & 63;
    const int ty  = threadIdx.x >> 6;
    const int p0  = pt * 64, c0 = ct * 64;
    const float* xb  = x  + (size_t)b * C_IN * P_SP;
    float*       xtb = xT + (size_t)b * P_SP * C_IN;

    #pragma unroll
    for (int k = ty; k < 64; k += 4) {
        int p = p0 + tx;
        t[k][tx] = (p < P_SP) ? xb[(size_t)(c0 + k) * P_SP + p] : 0.0f;
    }
    __syncthreads();
    #pragma unroll
    for (int k = ty; k < 64; k += 4) {
        int p = p0 + k;
        if (p < P_SP) xtb[(size_t)p * C_IN + c0 + tx] = t[tx][k];
    }
}

// ---------------------------------------------------------------------------
// Symmetric Gram, 64x64 tiles, no atomics (unchanged from R6 — measured via
// this round once scatter shrinks).
// ---------------------------------------------------------------------------
__global__ __launch_bounds__(256, 6) void gram64(
    const float* __restrict__ xT, float* __restrict__ G)
{
    __shared__ __align__(16) float AB[2][28 * 64];   // 7 KB per buffer

    const int tid  = threadIdx.x;
    const int tx   = tid & 15;
    const int ty   = tid >> 4;
    const int wid  = tid >> 6;
    const int lane = tid & 63;

    const int id  = blockIdx.x;      // 0..1151
    const int xcd = id & 7;
    const int sub = id >> 3;
    const int b   = xcd + 8 * (sub / NTP64);
    const int t   = sub % NTP64;
    const int it  = IT64[t];
    const int jt  = JT64[t];
    const int cbA = it * 64, cbB = jt * 64;

    const float* xb = xT + (size_t)b * P_SP * C_IN;

    #define ISSUE(P0, BUF) do {                                               \
        for (int k = wid; k < 7; k += 4) {                                    \
            int fr   = 4 * k + (lane >> 4);                                   \
            int aSel = fr < 14;                                               \
            int pr   = aSel ? fr : fr - 14;                                   \
            int cb_  = aSel ? cbA : cbB;                                      \
            const float* g = xb + (size_t)((P0) + pr) * C_IN + cb_            \
                             + (lane & 15) * 4;                               \
            gload_lds16(g, &AB[BUF][k * 256]);                                \
        }                                                                     \
    } while (0)

    float acc[4][4];
    #pragma unroll
    for (int r = 0; r < 4; ++r)
        #pragma unroll
        for (int c = 0; c < 4; ++c) acc[r][c] = 0.0f;

    ISSUE(0, 0);
    __syncthreads();

    for (int ch = 0; ch < 14; ++ch) {
        const int cur = ch & 1;
        if (ch + 1 < 14) ISSUE((ch + 1) * 14, cur ^ 1);
        #pragma unroll
        for (int pp = 0; pp < 14; ++pp) {
            float4 a = *(const float4*)(&AB[cur][pp * 64 + ty * 4]);
            float4 v = *(const float4*)(&AB[cur][(14 + pp) * 64 + tx * 4]);
            float av[4] = {a.x, a.y, a.z, a.w};
            float bv[4] = {v.x, v.y, v.z, v.w};
            #pragma unroll
            for (int r = 0; r < 4; ++r)
                #pragma unroll
                for (int c = 0; c < 4; ++c)
                    acc[r][c] = fmaf(av[r], bv[c], acc[r][c]);
        }
        __syncthreads();
    }
    #undef ISSUE

    float* gt = G + (size_t)(b * NTP64 + t) * 4096;
    #pragma unroll
    for (int r = 0; r < 4; ++r) {
        float4 o = make_float4(acc[r][0], acc[r][1], acc[r][2], acc[r][3]);
        *(float4*)(&gt[(ty * 4 + r) * 64 + tx * 4]) = o;
    }
}

// ---------------------------------------------------------------------------
// Scatter, phase-split: (1) batch-load G + ALL 8 param float4s to registers,
// (2) register-only address/value math, (3) 32 back-to-back ds_add_f32 with
// NO interleaved LDS reads. Rationale: every DS op counts in lgkmcnt, so a
// pk[] read between atomics forces a full LDS drain (R8: VGPR=52 proved the
// compiler re-read pk per emission). Grid = 32*ng, ng=16 -> 2 blocks/CU.
// ---------------------------------------------------------------------------
__global__ __launch_bounds__(256) void scatter64(
    const float* __restrict__ G,
    const int* __restrict__ h1, const float* __restrict__ s1,
    const int* __restrict__ h2, const float* __restrict__ s2,
    float* __restrict__ dest, int ng, int mode)
{
    __shared__ __align__(16) float hist[D_PROJ];      // 32 KB
    __shared__ __align__(16) float4 pk[C_IN];         // 8 KB packed params

    const int tid = threadIdx.x;
    const int id  = blockIdx.x;
    const int xcd = id & 7;
    const int sub = id >> 3;
    const int b   = xcd + 8 * (sub / ng);
    const int grp = sub % ng;

    for (int k = tid; k < C_IN; k += 256) {
        float4 w;
        w.x = __int_as_float(h1[k]);  w.y = s1[k];
        w.z = __int_as_float(h2[k]);  w.w = s2[k];
        pk[k] = w;
    }
    for (int k = tid * 4; k < D_PROJ; k += 1024)
        *(float4*)(hist + k) = make_float4(0.f, 0.f, 0.f, 0.f);
    __syncthreads();

    const int rr  = tid >> 4;        // 0..15: row sub-index
    const int c0t = (tid & 15) * 4;  // col start

    for (int t = grp; t < NTP64; t += ng) {
        const int it = IT64[t], jt = JT64[t];
        const int diag = (it == jt);
        const float* gt = G + (size_t)(b * NTP64 + t) * 4096;

        // Phase 1: ALL loads up-front, into named registers.
        float4 g[4];
        #pragma unroll
        for (int n = 0; n < 4; ++n)
            g[n] = *(const float4*)(gt + n * 1024 + tid * 4);
        float4 colp[4], rowp[4];
        #pragma unroll
        for (int k = 0; k < 4; ++k) colp[k] = pk[jt * 64 + c0t + k];
        #pragma unroll
        for (int n = 0; n < 4; ++n) rowp[n] = pk[it * 64 + n * 16 + rr];

        // Phase 2+3: register math + fire-and-forget atomics, no LDS reads.
        #pragma unroll
        for (int n = 0; n < 4; ++n) {
            const int   hA = __float_as_int(rowp[n].x);
            const float sA = rowp[n].y;
            const int   hM = __float_as_int(rowp[n].z);
            const float sM = rowp[n].w;
            const float gv[4] = {g[n].x, g[n].y, g[n].z, g[n].w};
            #pragma unroll
            for (int k = 0; k < 4; ++k) {
                const int d1 = (hA + __float_as_int(colp[k].z)) & (D_PROJ - 1);
                fadd_native(&hist[d1], sA * colp[k].w * gv[k]);
                if (!diag) {
                    const int d2 = (__float_as_int(colp[k].x) + hM) & (D_PROJ - 1);
                    fadd_native(&hist[d2], colp[k].y * sM * gv[k]);
                }
            }
        }
    }
    __syncthreads();

    if (mode == 1) {
        float* pb = dest + (size_t)(b * ng + grp) * D_PROJ;
        for (int k = tid * 4; k < D_PROJ; k += 1024)
            *(float4*)(pb + k) = *(const float4*)(hist + k);
    } else {
        float* pb = dest + (size_t)b * D_PROJ;
        for (int k = tid; k < D_PROJ; k += 256) fadd_native(&pb[k], hist[k]);
    }
}

// ---------------------------------------------------------------------------
__device__ inline float ssqrt_scale(float v, float inv)
{
    float r = sqrtf(fabsf(v) + 1e-8f) * inv;
    return (v > 0.0f) ? r : ((v < 0.0f) ? -r : 0.0f);
}

__global__ __launch_bounds__(256) void finalize_partial(
    const float* __restrict__ partial, float* __restrict__ out, int ns)
{
    const int b   = blockIdx.x;
    const int tid = threadIdx.x;
    const float* base = partial + (size_t)b * ns * D_PROJ;

    float4 acc[8];
    #pragma unroll
    for (int n = 0; n < 8; ++n) acc[n] = make_float4(0.f, 0.f, 0.f, 0.f);

    for (int t = 0; t < ns; ++t) {
        const float* bt = base + (size_t)t * D_PROJ;
        #pragma unroll
        for (int n = 0; n < 8; ++n) {
            float4 v = *(const float4*)(bt + tid * 4 + n * 1024);
            acc[n].x += v.x; acc[n].y += v.y; acc[n].z += v.z; acc[n].w += v.w;
        }
    }

    float s = 0.0f;
    #pragma unroll
    for (int n = 0; n < 8; ++n)
        s += fabsf(acc[n].x) + fabsf(acc[n].y) + fabsf(acc[n].z) + fabsf(acc[n].w);
    #pragma unroll
    for (int off = 32; off > 0; off >>= 1) s += __shfl_down(s, off, 64);
    __shared__ float red[4];
    if ((tid & 63) == 0) red[tid >> 6] = s;
    __syncthreads();
    float total = red[0] + red[1] + red[2] + red[3];
    float inv   = 1.0f / fmaxf(sqrtf(total + (float)D_PROJ * 1e-8f), 1e-12f);

    float* ob = out + (size_t)b * D_PROJ;
    #pragma unroll
    for (int n = 0; n < 8; ++n) {
        const int k = tid * 4 + n * 1024;
        float4 a = acc[n];
        float4 r;
        r.x = ssqrt_scale(a.x, inv);
        r.y = ssqrt_scale(a.y, inv);
        r.z = ssqrt_scale(a.z, inv);
        r.w = ssqrt_scale(a.w, inv);
        *(float4*)(ob + k) = r;
    }
}

__global__ __launch_bounds__(256) void finalize_inplace(float* __restrict__ out)
{
    const int b = blockIdx.x;
    float* p = out + (size_t)b * D_PROJ;
    const int tid = threadIdx.x;

    float s = 0.0f;
    for (int d = tid; d < D_PROJ; d += 256) s += fabsf(p[d]);
    #pragma unroll
    for (int off = 32; off > 0; off >>= 1) s += __shfl_down(s, off, 64);
    __shared__ float red[4];
    if ((tid & 63) == 0) red[tid >> 6] = s;
    __syncthreads();
    float total = red[0] + red[1] + red[2] + red[3];
    float inv   = 1.0f / fmaxf(sqrtf(total + (float)D_PROJ * 1e-8f), 1e-12f);

    for (int d = tid; d < D_PROJ; d += 256) {
        float v = p[d];
        float r = sqrtf(fabsf(v) + 1e-8f) * inv;
        p[d] = (v > 0.0f) ? r : ((v < 0.0f) ? -r : 0.0f);
    }
}

// ---------------------------------------------------------------------------
// Legacy fused fallback (tiny ws).
// ---------------------------------------------------------------------------
__global__ __launch_bounds__(256) void gram_scatter_legacy(
    const float* __restrict__ x,
    const int* __restrict__ h1, const float* __restrict__ s1,
    const int* __restrict__ h2, const float* __restrict__ s2,
    float* __restrict__ pool)
{
    __shared__ float accL[D_PROJ];
    __shared__ __align__(16) float As[14 * LDA];
    __shared__ __align__(16) float Bs[14 * LDA];
    __shared__ int   h1L[128];
    __shared__ float s1L[128];
    __shared__ int   h2L[128];
    __shared__ float s2L[128];

    const int tid = threadIdx.x;
    const int tx  = tid & 15;
    const int ty  = tid >> 4;
    const int id  = blockIdx.x;
    const int xcd = id & 7;
    const int rem = id >> 3;
    const int tile = rem & 15;
    const int b   = xcd + 8 * (rem >> 4);
    const int it  = tile >> 2;
    const int jt  = tile & 3;

    if (tid < 128) {
        h1L[tid] = h1[it * 128 + tid];
        s1L[tid] = s1[it * 128 + tid];
        h2L[tid] = h2[jt * 128 + tid];
        s2L[tid] = s2[jt * 128 + tid];
    }
    for (int k = tid; k < D_PROJ; k += 256) accL[k] = 0.0f;

    const float* xi = x + ((size_t)b * C_IN + it * 128) * P_SP;
    const float* xj = x + ((size_t)b * C_IN + jt * 128) * P_SP;

    float acc[8][8];
    #pragma unroll
    for (int r = 0; r < 8; ++r)
        #pragma unroll
        for (int c = 0; c < 8; ++c) acc[r][c] = 0.0f;

    for (int ch = 0; ch < 14; ++ch) {
        const int p0 = ch * 14;
        __syncthreads();
        #pragma unroll
        for (int e = 0; e < 7; ++e) {
            int idx = e * 256 + tid;
            int il  = idx / 14;
            int pp  = idx - il * 14;
            As[pp * LDA + il] = xi[il * P_SP + p0 + pp];
            Bs[pp * LDA + il] = xj[il * P_SP + p0 + pp];
        }
        __syncthreads();
        #pragma unroll
        for (int pp = 0; pp < 14; ++pp) {
            const float* ap = &As[pp * LDA];
            const float* bp = &Bs[pp * LDA];
            float4 a0 = *(const float4*)(ap + ty * 4);
            float4 a1 = *(const float4*)(ap + 64 + ty * 4);
            float4 b0 = *(const float4*)(bp + tx * 4);
            float4 b1 = *(const float4*)(bp + 64 + tx * 4);
            float av[8] = {a0.x, a0.y, a0.z, a0.w, a1.x, a1.y, a1.z, a1.w};
            float bv[8] = {b0.x, b0.y, b0.z, b0.w, b1.x, b1.y, b1.z, b1.w};
            #pragma unroll
            for (int r = 0; r < 8; ++r)
                #pragma unroll
                for (int c = 0; c < 8; ++c)
                    acc[r][c] = fmaf(av[r], bv[c], acc[r][c]);
        }
    }

    #pragma unroll
    for (int r = 0; r < 8; ++r) {
        int   il = (r < 4) ? (ty * 4 + r) : (64 + ty * 4 + (r - 4));
        int   hA = h1L[il];
        float sA = s1L[il];
        #pragma unroll
        for (int c = 0; c < 8; ++c) {
            int jl = (c < 4) ? (tx * 4 + c) : (64 + tx * 4 + (c - 4));
            int d  = (hA + h2L[jl]) & (D_PROJ - 1);
            fadd_native(&accL[d], sA * s2L[jl] * acc[r][c]);
        }
    }
    __syncthreads();

    float* pb = pool + (size_t)b * D_PROJ;
    for (int k = tid; k < D_PROJ; k += 256) fadd_native(&pb[k], accL[k]);
}

// ---------------------------------------------------------------------------
extern "C" void kernel_launch(void* const* d_in, const int* in_sizes, int n_in,
                              void* d_out, int out_size, void* d_ws, size_t ws_size,
                              hipStream_t stream)
{
    const float* x  = (const float*)d_in[0];   // [32, 512, 14, 14]
    const float* S1 = (const float*)d_in[1];   // [512, 8192]
    const float* S2 = (const float*)d_in[2];   // [512, 8192]
    float* out = (float*)d_out;                // [32, 8192]

    char* ws = (char*)d_ws;
    int*   h1 = (int*)(ws);
    float* s1 = (float*)(ws + 2048);
    int*   h2 = (int*)(ws + 4096);
    float* s2 = (float*)(ws + 6144);

    const size_t XT_BYTES = (size_t)NBATCH * P_SP * C_IN * sizeof(float);       // 12.85 MB
    const size_t G_BYTES  = (size_t)NBATCH * NTP64 * 4096 * sizeof(float);      // 18.87 MB
    const size_t SLICE    = (size_t)NBATCH * D_PROJ * sizeof(float);            //  1.05 MB per group

    float* xT      = (float*)(ws + 8192);
    float* G       = (float*)(ws + 8192 + XT_BYTES);
    float* partial = (float*)(ws + 8192 + XT_BYTES + G_BYTES);

    const size_t base = 8192 + XT_BYTES + G_BYTES;

    if (ws_size >= base) {
        int ng = 0;
        if      (ws_size >= base + 16 * SLICE) ng = 16;
        else if (ws_size >= base +  8 * SLICE) ng = 8;

        prep<<<2048, 256, 0, stream>>>(S1, S2, x, h1, s1, h2, s2, xT, 1);
        gram64<<<NBATCH * NTP64, 256, 0, stream>>>(xT, G);
        if (ng > 0) {
            scatter64<<<NBATCH * ng, 256, 0, stream>>>(G, h1, s1, h2, s2, partial, ng, 1);
            finalize_partial<<<NBATCH, 256, 0, stream>>>(partial, out, ng);
        } else {
            hipMemsetAsync(d_out, 0, (size_t)out_size * sizeof(float), stream);
            scatter64<<<NBATCH * 8, 256, 0, stream>>>(G, h1, s1, h2, s2, out, 8, 0);
            finalize_inplace<<<NBATCH, 256, 0, stream>>>(out);
        }
    } else {
        hipMemsetAsync(d_out, 0, (size_t)out_size * sizeof(float), stream);
        prep<<<1024, 256, 0, stream>>>(S1, S2, x, h1, s1, h2, s2, (float*)nullptr, 0);
        gram_scatter_legacy<<<512, 256, 0, stream>>>(x, h1, s1, h2, s2, out);
        finalize_inplace<<<NBATCH, 256, 0, stream>>>(out);
    }
}